// Round 1
// baseline (129.595 us; speedup 1.0000x reference)
//
#include <hip/hip_runtime.h>
#include <hip/hip_bf16.h>
#include <cstdint>
#include <cstddef>

#define VOCAB  50000
#define EMBED  256
#define HIDDEN 512
#define BATCH  64
#define SEQ    200
#define H2     1024
#define XDIM   1280   // EMBED + H2
#define G3     1536   // 3*HIDDEN

typedef __attribute__((ext_vector_type(8))) short short8;
typedef __attribute__((ext_vector_type(4))) float f32x4;

__device__ __forceinline__ short f2bf(float f) {
  uint32_t u = __builtin_bit_cast(uint32_t, f);
  uint32_t r = (u + 0x7fffu + ((u >> 16) & 1u)) >> 16;
  return (short)(r & 0xffffu);
}

// ---------------------------------------------------------------------------
// Generic GEMM: C(64 x N) = A(64 x K) * B(N x K)^T  (+ bias)
// A,B read as f32, converted to bf16, MFMA 16x16x32, f32 accumulate.
// MODE 0: C = acc + bias[n] (direct store).  MODE 1: atomicAdd(C, acc) (split-K).
// grid.x = ceil(N/64), grid.y = ksplit; each y-slice covers klen of K.
// ---------------------------------------------------------------------------
template<int MODE>
__launch_bounds__(256)
__global__ void gemm_a64(const float* __restrict__ A, int lda,
                         const float* __restrict__ B, int ldb,
                         const float* __restrict__ bias,
                         float* __restrict__ C, int ldc,
                         int N, int klen) {
  __shared__ __align__(16) short As[4 * 64 * 8];  // fragment-linear A chunk (64x32 bf16)
  const int tid  = threadIdx.x;
  const int wave = tid >> 6, lane = tid & 63;
  const int l15  = lane & 15, lk = lane >> 4;
  const int ncol = blockIdx.x * 64 + wave * 16;
  const int kbeg = blockIdx.y * klen;

  f32x4 acc0 = {0,0,0,0}, acc1 = {0,0,0,0}, acc2 = {0,0,0,0}, acc3 = {0,0,0,0};

  // staging coordinates: thread tid stages frag (mt = tid>>6, frag-lane = tid&63)
  const int sl  = tid & 63;
  const int sm  = (tid >> 6) * 16 + (sl & 15);   // A row
  const int skb = (sl >> 4) * 8;                 // k offset within chunk

  int nrow = ncol + l15; if (nrow > N - 1) nrow = N - 1;
  const float* Bbase = B + (size_t)nrow * ldb + lk * 8;

  for (int kc = kbeg; kc < kbeg + klen; kc += 32) {
    // ---- stage A chunk (f32 -> bf16) into fragment-linear LDS
    {
      const float4* ap = reinterpret_cast<const float4*>(A + (size_t)sm * lda + kc + skb);
      float4 v0 = ap[0], v1 = ap[1];
      short8 fr;
      fr[0]=f2bf(v0.x); fr[1]=f2bf(v0.y); fr[2]=f2bf(v0.z); fr[3]=f2bf(v0.w);
      fr[4]=f2bf(v1.x); fr[5]=f2bf(v1.y); fr[6]=f2bf(v1.z); fr[7]=f2bf(v1.w);
      *reinterpret_cast<short8*>(&As[tid * 8]) = fr;
    }
    __syncthreads();
    // ---- B fragment straight from global (row nrow, 8 consecutive k)
    short8 bf;
    {
      const float4* bp = reinterpret_cast<const float4*>(Bbase + kc);
      float4 v0 = bp[0], v1 = bp[1];
      bf[0]=f2bf(v0.x); bf[1]=f2bf(v0.y); bf[2]=f2bf(v0.z); bf[3]=f2bf(v0.w);
      bf[4]=f2bf(v1.x); bf[5]=f2bf(v1.y); bf[6]=f2bf(v1.z); bf[7]=f2bf(v1.w);
    }
    short8 a0 = *reinterpret_cast<const short8*>(&As[(0*64 + lane)*8]);
    short8 a1 = *reinterpret_cast<const short8*>(&As[(1*64 + lane)*8]);
    short8 a2 = *reinterpret_cast<const short8*>(&As[(2*64 + lane)*8]);
    short8 a3 = *reinterpret_cast<const short8*>(&As[(3*64 + lane)*8]);
    acc0 = __builtin_amdgcn_mfma_f32_16x16x32_bf16(a0, bf, acc0, 0, 0, 0);
    acc1 = __builtin_amdgcn_mfma_f32_16x16x32_bf16(a1, bf, acc1, 0, 0, 0);
    acc2 = __builtin_amdgcn_mfma_f32_16x16x32_bf16(a2, bf, acc2, 0, 0, 0);
    acc3 = __builtin_amdgcn_mfma_f32_16x16x32_bf16(a3, bf, acc3, 0, 0, 0);
    __syncthreads();
  }

  const int n = ncol + l15;
  if (n < N) {
    if (MODE == 0) {
      float bv = bias[n];
      #pragma unroll
      for (int r = 0; r < 4; ++r) {
        C[(size_t)(0*16 + lk*4 + r) * ldc + n] = acc0[r] + bv;
        C[(size_t)(1*16 + lk*4 + r) * ldc + n] = acc1[r] + bv;
        C[(size_t)(2*16 + lk*4 + r) * ldc + n] = acc2[r] + bv;
        C[(size_t)(3*16 + lk*4 + r) * ldc + n] = acc3[r] + bv;
      }
    } else {
      #pragma unroll
      for (int r = 0; r < 4; ++r) {
        atomicAdd(&C[(size_t)(0*16 + lk*4 + r) * ldc + n], acc0[r]);
        atomicAdd(&C[(size_t)(1*16 + lk*4 + r) * ldc + n], acc1[r]);
        atomicAdd(&C[(size_t)(2*16 + lk*4 + r) * ldc + n], acc2[r]);
        atomicAdd(&C[(size_t)(3*16 + lk*4 + r) * ldc + n], acc3[r]);
      }
    }
  }
}

// ---------------------------------------------------------------------------
__global__ void build_x(const int* __restrict__ idx, const float* __restrict__ embed,
                        const float* __restrict__ weighted, float* __restrict__ x) {
  int b = blockIdx.x, tid = threadIdx.x;
  int e = idx[b];
  for (int k = tid; k < EMBED; k += 256) x[(size_t)b*XDIM + k] = embed[(size_t)e*EMBED + k];
  for (int k = tid; k < H2;    k += 256) x[(size_t)b*XDIM + EMBED + k] = weighted[(size_t)b*H2 + k];
}

__global__ void gru_gates(const float* __restrict__ gx, const float* __restrict__ gh,
                          const float* __restrict__ b_ih, const float* __restrict__ b_hh,
                          const float* __restrict__ h0, float* __restrict__ state,
                          float* __restrict__ out_state) {
  int i = blockIdx.x * 256 + threadIdx.x;   // < 64*512
  int b = i >> 9, h = i & 511;
  float xr = gx[(size_t)b*G3 + h]            + b_ih[h];
  float xz = gx[(size_t)b*G3 + HIDDEN + h]   + b_ih[HIDDEN + h];
  float xn = gx[(size_t)b*G3 + 2*HIDDEN + h] + b_ih[2*HIDDEN + h];
  float hr = gh[(size_t)b*G3 + h]            + b_hh[h];
  float hz = gh[(size_t)b*G3 + HIDDEN + h]   + b_hh[HIDDEN + h];
  float hn = gh[(size_t)b*G3 + 2*HIDDEN + h] + b_hh[2*HIDDEN + h];
  float r = 1.f / (1.f + __expf(-(xr + hr)));
  float z = 1.f / (1.f + __expf(-(xz + hz)));
  float n = tanhf(xn + r * hn);
  float st = (1.f - z) * n + z * h0[(size_t)b*HIDDEN + h];
  state[(size_t)b*HIDDEN + h] = st;
  out_state[(size_t)b*HIDDEN + h] = st;
}

// score_c only where (encoded_idx != 0) && (encoded_idx == input_idx): exact f32
__global__ void sparse_scc(const int* __restrict__ eidx, const int* __restrict__ iidx,
                           const float* __restrict__ enc, const float* __restrict__ wc_w,
                           const float* __restrict__ wc_b, const float* __restrict__ state,
                           float* __restrict__ scc) {
  int b = blockIdx.x, tid = threadIdx.x;
  int in0 = iidx[b];
  __shared__ float red[256];
  for (int s = 0; s < SEQ; ++s) {
    int e = eidx[b*SEQ + s];
    bool active = (e != 0) && (e == in0);
    if (active) {
      const float4* er = reinterpret_cast<const float4*>(enc + (size_t)b*SEQ*H2 + (size_t)s*H2);
      float part = 0.f;
      for (int h = tid; h < HIDDEN; h += 256) {
        const float4* wr = reinterpret_cast<const float4*>(wc_w + (size_t)h*H2);
        float d = wc_b[h];
        for (int k = 0; k < H2/4; ++k) {
          float4 a = er[k], w = wr[k];
          d += a.x*w.x + a.y*w.y + a.z*w.z + a.w*w.w;
        }
        part += tanhf(d) * state[(size_t)b*HIDDEN + h];
      }
      red[tid] = part;
      __syncthreads();
      for (int off = 128; off > 0; off >>= 1) {
        if (tid < off) red[tid] += red[tid + off];
        __syncthreads();
      }
      if (tid == 0) scc[b*SEQ + s] = red[0];
      __syncthreads();
    } else {
      if (tid == 0) scc[b*SEQ + s] = 0.f;
    }
  }
}

__device__ __forceinline__ void omerge(float& m, float& s, float m2, float s2) {
  if (m2 > m) { s = s * __expf(m - m2) + s2; m = m2; }
  else if (m2 != -INFINITY) { s += s2 * __expf(m2 - m); }
}

// per-row online max + sum(exp(x-max)) over [S_g (50000) ++ scc (200)]
__global__ void softmax_stats(const float* __restrict__ Sg, const float* __restrict__ scc,
                              float* __restrict__ stats) {
  int b = blockIdx.x, tid = threadIdx.x;
  const float4* p = reinterpret_cast<const float4*>(Sg + (size_t)b*VOCAB);
  float m = -INFINITY, s = 0.f;
  for (int i = tid; i < VOCAB/4; i += 256) {
    float4 v = p[i];
    omerge(m, s, v.x, 1.f); omerge(m, s, v.y, 1.f);
    omerge(m, s, v.z, 1.f); omerge(m, s, v.w, 1.f);
  }
  for (int i = tid; i < SEQ; i += 256) omerge(m, s, scc[b*SEQ + i], 1.f);
  for (int off = 1; off < 64; off <<= 1) {
    float m2 = __shfl_xor(m, off), s2 = __shfl_xor(s, off);
    omerge(m, s, m2, s2);
  }
  __shared__ float ms[4], ss[4];
  int wave = tid >> 6, lane = tid & 63;
  if (lane == 0) { ms[wave] = m; ss[wave] = s; }
  __syncthreads();
  if (tid == 0) {
    float M = ms[0], S = ss[0];
    for (int w = 1; w < 4; ++w) omerge(M, S, ms[w], ss[w]);
    stats[b*2] = M; stats[b*2+1] = S;
  }
}

__global__ void finalize_out(const float* __restrict__ Sg, const float* __restrict__ stats,
                             float* __restrict__ out0) {
  int g = blockIdx.x * 256 + threadIdx.x;   // exactly 800000
  int b = g / (VOCAB/4), i = g - b * (VOCAB/4);
  float M = stats[b*2], inv = 1.f / stats[b*2+1];
  float4 v = reinterpret_cast<const float4*>(Sg + (size_t)b*VOCAB)[i];
  float4 o;
  o.x = __expf(v.x - M) * inv; o.y = __expf(v.y - M) * inv;
  o.z = __expf(v.z - M) * inv; o.w = __expf(v.w - M) * inv;
  reinterpret_cast<float4*>(out0 + (size_t)b*VOCAB)[i] = o;
}

// scatter prob_c into out, compute attn-normalized weighted_new
__global__ void epilogue(const int* __restrict__ eidx, const int* __restrict__ iidx,
                         const float* __restrict__ scc, const float* __restrict__ stats,
                         const float* __restrict__ enc, float* __restrict__ out0,
                         float* __restrict__ wnew) {
  int b = blockIdx.x, tid = threadIdx.x;
  __shared__ float attn_sh[SEQ];
  __shared__ float fnorm_sh;
  float M = stats[b*2], inv = 1.f / stats[b*2+1];
  int in0 = iidx[b];
  if (tid < SEQ) {
    int e = eidx[b*SEQ + tid];
    float p = __expf(scc[b*SEQ + tid] - M) * inv;
    atomicAdd(&out0[(size_t)b*VOCAB + e], p);
    attn_sh[tid] = (e == in0) ? p : 0.f;
  }
  __syncthreads();
  if (tid == 0) {
    float s = 0.f;
    for (int i = 0; i < SEQ; ++i) s += attn_sh[i];
    fnorm_sh = (s > 0.f) ? 1.f / s : 1.f;
  }
  __syncthreads();
  float f = fnorm_sh;
  float a0 = 0, a1 = 0, a2 = 0, a3 = 0;
  const float4* ep = reinterpret_cast<const float4*>(enc + (size_t)b*SEQ*H2);
  for (int s = 0; s < SEQ; ++s) {
    float a = attn_sh[s];
    if (a != 0.f) {                       // wave-uniform branch, almost always skipped
      a *= f;
      float4 v = ep[(size_t)s*(H2/4) + tid];
      a0 += a*v.x; a1 += a*v.y; a2 += a*v.z; a3 += a*v.w;
    }
  }
  float4 o = {a0, a1, a2, a3};
  reinterpret_cast<float4*>(wnew + (size_t)b*H2)[tid] = o;
}

// ---------------------------------------------------------------------------
extern "C" void kernel_launch(void* const* d_in, const int* in_sizes, int n_in,
                              void* d_out, int out_size, void* d_ws, size_t ws_size,
                              hipStream_t stream) {
  (void)in_sizes; (void)n_in; (void)out_size; (void)ws_size;
  const int*   input_idx  = (const int*)d_in[0];
  const float* encoded    = (const float*)d_in[1];
  const int*   enc_idx    = (const int*)d_in[2];
  const float* prev_state = (const float*)d_in[3];
  const float* weighted   = (const float*)d_in[4];
  const float* embed      = (const float*)d_in[6];
  const float* w_ih       = (const float*)d_in[7];
  const float* w_hh       = (const float*)d_in[8];
  const float* b_ih       = (const float*)d_in[9];
  const float* b_hh       = (const float*)d_in[10];
  const float* wo_w       = (const float*)d_in[11];
  const float* wo_b       = (const float*)d_in[12];
  const float* wc_w       = (const float*)d_in[13];
  const float* wc_b       = (const float*)d_in[14];

  float* out0      = (float*)d_out;                          // 64 x 50000
  float* out_state = out0 + (size_t)BATCH * VOCAB;           // 64 x 512
  float* out_wnew  = out_state + BATCH * HIDDEN;             // 64 x 1024

  float* ws    = (float*)d_ws;
  float* x     = ws;                           // 64x1280
  float* gx    = x     + BATCH * XDIM;         // 64x1536
  float* gh    = gx    + BATCH * G3;           // 64x1536
  float* state = gh    + BATCH * G3;           // 64x512
  float* scc   = state + BATCH * HIDDEN;       // 64x200
  float* stats = scc   + BATCH * SEQ;          // 64x2
  float* Sg    = stats + 128;                  // 64x50000

  hipMemsetAsync(gx, 0, (size_t)2 * BATCH * G3 * sizeof(float), stream);

  build_x<<<BATCH, 256, 0, stream>>>(input_idx, embed, weighted, x);
  // gx = x @ w_ih^T (K=1280, split 8)
  gemm_a64<1><<<dim3(G3/64, 8), 256, 0, stream>>>(x, XDIM, w_ih, XDIM, nullptr, gx, G3, G3, XDIM/8);
  // gh = h @ w_hh^T (K=512, split 4)
  gemm_a64<1><<<dim3(G3/64, 4), 256, 0, stream>>>(prev_state, HIDDEN, w_hh, HIDDEN, nullptr, gh, G3, G3, HIDDEN/4);
  gru_gates<<<(BATCH*HIDDEN)/256, 256, 0, stream>>>(gx, gh, b_ih, b_hh, prev_state, state, out_state);
  // S_g = state @ wo_w^T + wo_b
  gemm_a64<0><<<dim3((VOCAB+63)/64, 1), 256, 0, stream>>>(state, HIDDEN, wo_w, HIDDEN, wo_b, Sg, VOCAB, VOCAB, HIDDEN);
  sparse_scc<<<BATCH, 256, 0, stream>>>(enc_idx, input_idx, encoded, wc_w, wc_b, state, scc);
  softmax_stats<<<BATCH, 256, 0, stream>>>(Sg, scc, stats);
  finalize_out<<<(BATCH*VOCAB/4)/256, 256, 0, stream>>>(Sg, stats, out0);
  epilogue<<<BATCH, 256, 0, stream>>>(enc_idx, input_idx, scc, stats, encoded, out0, out_wnew);
}

// Round 2
// 91.700 us; speedup vs baseline: 1.4133x; 1.4133x over previous
//
#include <hip/hip_runtime.h>
#include <hip/hip_bf16.h>
#include <cstdint>
#include <cstddef>

#define VOCAB  50000
#define EMBED  256
#define HIDDEN 512
#define BATCH  64
#define SEQ    200
#define H2     1024
#define XDIM   1280   // EMBED + H2
#define G3     1536   // 3*HIDDEN
#define NPART  8      // softmax stats partials per row
#define V4     (VOCAB/4)   // 12500 float4 per row
#define CHUNK4 1563        // ceil(12500/8)

typedef __attribute__((ext_vector_type(8))) short short8;
typedef __attribute__((ext_vector_type(4))) float f32x4;

__device__ __forceinline__ short f2bf(float f) {
  uint32_t u = __builtin_bit_cast(uint32_t, f);
  uint32_t r = (u + 0x7fffu + ((u >> 16) & 1u)) >> 16;
  return (short)(r & 0xffffu);
}

__device__ __forceinline__ void omerge(float& m, float& s, float m2, float s2) {
  if (m2 > m) { s = s * __expf(m - m2) + s2; m = m2; }
  else if (m2 != -INFINITY) { s += s2 * __expf(m2 - m); }
}

// ---------------------------------------------------------------------------
// Fused GRU input GEMMs: grid (24, 12).
//   slice < 8 : gxp[slice] = x[:, k-slice] @ w_ih[:, k-slice]^T   (x gathered
//               on the fly from embed[input_idx] ++ weighted, klen=160)
//   slice >= 8: ghp[slice-8] = h0[:, k-slice] @ w_hh[:, k-slice]^T (klen=128)
// C(64 x 1536) partial slices, f32 plain store (no atomics, no pre-zero).
// ---------------------------------------------------------------------------
__launch_bounds__(256)
__global__ void gru_gemm(const int* __restrict__ idx, const float* __restrict__ embed,
                         const float* __restrict__ weighted, const float* __restrict__ h0,
                         const float* __restrict__ w_ih, const float* __restrict__ w_hh,
                         float* __restrict__ gxp, float* __restrict__ ghp) {
  __shared__ __align__(16) short As[4 * 64 * 8];
  const int tid  = threadIdx.x;
  const int wave = tid >> 6, lane = tid & 63;
  const int l15  = lane & 15, lk = lane >> 4;
  const int slice = blockIdx.y;
  const bool isX  = slice < 8;
  const float* B  = isX ? w_ih : w_hh;
  const int ldb   = isX ? XDIM : HIDDEN;
  const int kbeg  = isX ? slice * 160 : (slice - 8) * 128;
  const int kend  = kbeg + (isX ? 160 : 128);
  float* C = isX ? (gxp + (size_t)slice * BATCH * G3)
                 : (ghp + (size_t)(slice - 8) * BATCH * G3);
  const int ncol = blockIdx.x * 64 + wave * 16;

  f32x4 acc0 = {0,0,0,0}, acc1 = {0,0,0,0}, acc2 = {0,0,0,0}, acc3 = {0,0,0,0};

  const int sl  = tid & 63;
  const int sm  = (tid >> 6) * 16 + (sl & 15);   // A row (batch)
  const int skb = (sl >> 4) * 8;                 // k offset within 32-chunk

  const int nrow = ncol + l15;                   // < 1536 always
  const float* Bbase = B + (size_t)nrow * ldb + lk * 8;

  for (int kc = kbeg; kc < kend; kc += 32) {
    {
      const float4* ap;
      if (isX) {
        int col = kc + skb;
        if (col < EMBED) ap = reinterpret_cast<const float4*>(embed + (size_t)idx[sm] * EMBED + col);
        else             ap = reinterpret_cast<const float4*>(weighted + (size_t)sm * H2 + (col - EMBED));
      } else {
        ap = reinterpret_cast<const float4*>(h0 + (size_t)sm * HIDDEN + kc + skb);
      }
      float4 v0 = ap[0], v1 = ap[1];
      short8 fr;
      fr[0]=f2bf(v0.x); fr[1]=f2bf(v0.y); fr[2]=f2bf(v0.z); fr[3]=f2bf(v0.w);
      fr[4]=f2bf(v1.x); fr[5]=f2bf(v1.y); fr[6]=f2bf(v1.z); fr[7]=f2bf(v1.w);
      *reinterpret_cast<short8*>(&As[tid * 8]) = fr;
    }
    __syncthreads();
    short8 bf;
    {
      const float4* bp = reinterpret_cast<const float4*>(Bbase + kc);
      float4 v0 = bp[0], v1 = bp[1];
      bf[0]=f2bf(v0.x); bf[1]=f2bf(v0.y); bf[2]=f2bf(v0.z); bf[3]=f2bf(v0.w);
      bf[4]=f2bf(v1.x); bf[5]=f2bf(v1.y); bf[6]=f2bf(v1.z); bf[7]=f2bf(v1.w);
    }
    short8 a0 = *reinterpret_cast<const short8*>(&As[(0*64 + lane)*8]);
    short8 a1 = *reinterpret_cast<const short8*>(&As[(1*64 + lane)*8]);
    short8 a2 = *reinterpret_cast<const short8*>(&As[(2*64 + lane)*8]);
    short8 a3 = *reinterpret_cast<const short8*>(&As[(3*64 + lane)*8]);
    acc0 = __builtin_amdgcn_mfma_f32_16x16x32_bf16(a0, bf, acc0, 0, 0, 0);
    acc1 = __builtin_amdgcn_mfma_f32_16x16x32_bf16(a1, bf, acc1, 0, 0, 0);
    acc2 = __builtin_amdgcn_mfma_f32_16x16x32_bf16(a2, bf, acc2, 0, 0, 0);
    acc3 = __builtin_amdgcn_mfma_f32_16x16x32_bf16(a3, bf, acc3, 0, 0, 0);
    __syncthreads();
  }

  const int n = ncol + l15;
  #pragma unroll
  for (int r = 0; r < 4; ++r) {
    C[(size_t)(0*16 + lk*4 + r) * G3 + n] = acc0[r];
    C[(size_t)(1*16 + lk*4 + r) * G3 + n] = acc1[r];
    C[(size_t)(2*16 + lk*4 + r) * G3 + n] = acc2[r];
    C[(size_t)(3*16 + lk*4 + r) * G3 + n] = acc3[r];
  }
}

// ---------------------------------------------------------------------------
// Vocab GEMM: Sg(64 x 50000) = state(64x512) @ wo_w^T + wo_b
// ---------------------------------------------------------------------------
__launch_bounds__(256)
__global__ void gemm_vocab(const float* __restrict__ A,
                           const float* __restrict__ B,
                           const float* __restrict__ bias,
                           float* __restrict__ C) {
  __shared__ __align__(16) short As[4 * 64 * 8];
  const int tid  = threadIdx.x;
  const int wave = tid >> 6, lane = tid & 63;
  const int l15  = lane & 15, lk = lane >> 4;
  const int ncol = blockIdx.x * 64 + wave * 16;

  f32x4 acc0 = {0,0,0,0}, acc1 = {0,0,0,0}, acc2 = {0,0,0,0}, acc3 = {0,0,0,0};

  const int sl  = tid & 63;
  const int sm  = (tid >> 6) * 16 + (sl & 15);
  const int skb = (sl >> 4) * 8;

  int nrow = ncol + l15; if (nrow > VOCAB - 1) nrow = VOCAB - 1;
  const float* Bbase = B + (size_t)nrow * HIDDEN + lk * 8;

  for (int kc = 0; kc < HIDDEN; kc += 32) {
    {
      const float4* ap = reinterpret_cast<const float4*>(A + (size_t)sm * HIDDEN + kc + skb);
      float4 v0 = ap[0], v1 = ap[1];
      short8 fr;
      fr[0]=f2bf(v0.x); fr[1]=f2bf(v0.y); fr[2]=f2bf(v0.z); fr[3]=f2bf(v0.w);
      fr[4]=f2bf(v1.x); fr[5]=f2bf(v1.y); fr[6]=f2bf(v1.z); fr[7]=f2bf(v1.w);
      *reinterpret_cast<short8*>(&As[tid * 8]) = fr;
    }
    __syncthreads();
    short8 bf;
    {
      const float4* bp = reinterpret_cast<const float4*>(Bbase + kc);
      float4 v0 = bp[0], v1 = bp[1];
      bf[0]=f2bf(v0.x); bf[1]=f2bf(v0.y); bf[2]=f2bf(v0.z); bf[3]=f2bf(v0.w);
      bf[4]=f2bf(v1.x); bf[5]=f2bf(v1.y); bf[6]=f2bf(v1.z); bf[7]=f2bf(v1.w);
    }
    short8 a0 = *reinterpret_cast<const short8*>(&As[(0*64 + lane)*8]);
    short8 a1 = *reinterpret_cast<const short8*>(&As[(1*64 + lane)*8]);
    short8 a2 = *reinterpret_cast<const short8*>(&As[(2*64 + lane)*8]);
    short8 a3 = *reinterpret_cast<const short8*>(&As[(3*64 + lane)*8]);
    acc0 = __builtin_amdgcn_mfma_f32_16x16x32_bf16(a0, bf, acc0, 0, 0, 0);
    acc1 = __builtin_amdgcn_mfma_f32_16x16x32_bf16(a1, bf, acc1, 0, 0, 0);
    acc2 = __builtin_amdgcn_mfma_f32_16x16x32_bf16(a2, bf, acc2, 0, 0, 0);
    acc3 = __builtin_amdgcn_mfma_f32_16x16x32_bf16(a3, bf, acc3, 0, 0, 0);
    __syncthreads();
  }

  const int n = ncol + l15;
  if (n < VOCAB) {
    float bv = bias[n];
    #pragma unroll
    for (int r = 0; r < 4; ++r) {
      C[(size_t)(0*16 + lk*4 + r) * VOCAB + n] = acc0[r] + bv;
      C[(size_t)(1*16 + lk*4 + r) * VOCAB + n] = acc1[r] + bv;
      C[(size_t)(2*16 + lk*4 + r) * VOCAB + n] = acc2[r] + bv;
      C[(size_t)(3*16 + lk*4 + r) * VOCAB + n] = acc3[r] + bv;
    }
  }
}

// ---------------------------------------------------------------------------
__launch_bounds__(256)
__global__ void gru_gates(const float* __restrict__ gxp, const float* __restrict__ ghp,
                          const float* __restrict__ b_ih, const float* __restrict__ b_hh,
                          const float* __restrict__ h0, float* __restrict__ out_state) {
  int i = blockIdx.x * 256 + threadIdx.x;   // < 64*512
  int b = i >> 9, h = i & 511;
  float xr = b_ih[h], xz = b_ih[HIDDEN + h], xn = b_ih[2*HIDDEN + h];
  #pragma unroll
  for (int s = 0; s < 8; ++s) {
    const float* g = gxp + (size_t)s * BATCH * G3 + (size_t)b * G3;
    xr += g[h]; xz += g[HIDDEN + h]; xn += g[2*HIDDEN + h];
  }
  float hr = b_hh[h], hz = b_hh[HIDDEN + h], hn = b_hh[2*HIDDEN + h];
  #pragma unroll
  for (int s = 0; s < 4; ++s) {
    const float* g = ghp + (size_t)s * BATCH * G3 + (size_t)b * G3;
    hr += g[h]; hz += g[HIDDEN + h]; hn += g[2*HIDDEN + h];
  }
  float r = 1.f / (1.f + __expf(-(xr + hr)));
  float z = 1.f / (1.f + __expf(-(xz + hz)));
  float n = tanhf(xn + r * hn);
  out_state[(size_t)b*HIDDEN + h] = (1.f - z) * n + z * h0[(size_t)b*HIDDEN + h];
}

// ---------------------------------------------------------------------------
// grid 512 = 64 rows x 8 parts. Each part: online max/sum-exp over a vocab
// chunk of Sg. Part 0 additionally computes scc (exact f32, only at the rare
// (e!=0 && e==input_idx) positions) and merges the 200 scc logits.
// ---------------------------------------------------------------------------
__launch_bounds__(256)
__global__ void stats_scc(const float* __restrict__ Sg, const int* __restrict__ eidx,
                          const int* __restrict__ iidx, const float* __restrict__ enc,
                          const float* __restrict__ wc_w, const float* __restrict__ wc_b,
                          const float* __restrict__ state,
                          float* __restrict__ scc, float* __restrict__ pstats) {
  __shared__ int   act[SEQ];
  __shared__ float red[256];
  __shared__ float ms[4], ss[4];
  const int b = blockIdx.x >> 3, part = blockIdx.x & 7;
  const int tid = threadIdx.x;

  if (part == 0) {
    int in0 = iidx[b];
    if (tid < SEQ) {
      int e = eidx[b*SEQ + tid];
      act[tid] = (e != 0 && e == in0);
      scc[b*SEQ + tid] = 0.f;
    }
    __syncthreads();
    for (int sq = 0; sq < SEQ; ++sq) {
      if (act[sq]) {
        const float4* er = reinterpret_cast<const float4*>(enc + (size_t)b*SEQ*H2 + (size_t)sq*H2);
        float part_sum = 0.f;
        for (int h = tid; h < HIDDEN; h += 256) {
          const float4* wr = reinterpret_cast<const float4*>(wc_w + (size_t)h*H2);
          float d = wc_b[h];
          for (int k = 0; k < H2/4; ++k) {
            float4 a = er[k], w = wr[k];
            d += a.x*w.x + a.y*w.y + a.z*w.z + a.w*w.w;
          }
          part_sum += tanhf(d) * state[(size_t)b*HIDDEN + h];
        }
        red[tid] = part_sum;
        __syncthreads();
        for (int off = 128; off > 0; off >>= 1) {
          if (tid < off) red[tid] += red[tid + off];
          __syncthreads();
        }
        if (tid == 0) scc[b*SEQ + sq] = red[0];
        __syncthreads();
      }
    }
    __syncthreads();
  }

  float m = -INFINITY, s = 0.f;
  const float4* p = reinterpret_cast<const float4*>(Sg + (size_t)b*VOCAB);
  const int i0 = part * CHUNK4;
  const int i1 = (i0 + CHUNK4 < V4) ? i0 + CHUNK4 : V4;
  for (int i = i0 + tid; i < i1; i += 256) {
    float4 v = p[i];
    omerge(m, s, v.x, 1.f); omerge(m, s, v.y, 1.f);
    omerge(m, s, v.z, 1.f); omerge(m, s, v.w, 1.f);
  }
  if (part == 0) {
    for (int i = tid; i < SEQ; i += 256) omerge(m, s, scc[b*SEQ + i], 1.f);
  }
  for (int off = 1; off < 64; off <<= 1) {
    float m2 = __shfl_xor(m, off), s2 = __shfl_xor(s, off);
    omerge(m, s, m2, s2);
  }
  int wave = tid >> 6, lane = tid & 63;
  if (lane == 0) { ms[wave] = m; ss[wave] = s; }
  __syncthreads();
  if (tid == 0) {
    float M = ms[0], S = ss[0];
    for (int w = 1; w < 4; ++w) omerge(M, S, ms[w], ss[w]);
    pstats[b*2*NPART + part*2]     = M;
    pstats[b*2*NPART + part*2 + 1] = S;
  }
}

__device__ __forceinline__ void merge_stats(const float* __restrict__ pstats, int b,
                                            float& M, float& S) {
  M = -INFINITY; S = 0.f;
  #pragma unroll
  for (int p = 0; p < NPART; ++p)
    omerge(M, S, pstats[b*2*NPART + 2*p], pstats[b*2*NPART + 2*p + 1]);
}

__launch_bounds__(256)
__global__ void finalize_out(const float* __restrict__ Sg, const float* __restrict__ pstats,
                             float* __restrict__ out0) {
  int g = blockIdx.x * 256 + threadIdx.x;   // exactly 800000
  int b = g / V4, i = g - b * V4;
  float M, S; merge_stats(pstats, b, M, S);
  float inv = 1.f / S;
  float4 v = reinterpret_cast<const float4*>(Sg + (size_t)b*VOCAB)[i];
  float4 o;
  o.x = __expf(v.x - M) * inv; o.y = __expf(v.y - M) * inv;
  o.z = __expf(v.z - M) * inv; o.w = __expf(v.w - M) * inv;
  reinterpret_cast<float4*>(out0 + (size_t)b*VOCAB)[i] = o;
}

__launch_bounds__(256)
__global__ void epilogue(const int* __restrict__ eidx, const int* __restrict__ iidx,
                         const float* __restrict__ scc, const float* __restrict__ pstats,
                         const float* __restrict__ enc, float* __restrict__ out0,
                         float* __restrict__ wnew) {
  int b = blockIdx.x, tid = threadIdx.x;
  __shared__ float attn_sh[SEQ];
  __shared__ float fnorm_sh;
  float M, S; merge_stats(pstats, b, M, S);
  float inv = 1.f / S;
  int in0 = iidx[b];
  if (tid < SEQ) {
    int e = eidx[b*SEQ + tid];
    float p = __expf(scc[b*SEQ + tid] - M) * inv;
    atomicAdd(&out0[(size_t)b*VOCAB + e], p);
    attn_sh[tid] = (e == in0) ? p : 0.f;
  }
  __syncthreads();
  if (tid == 0) {
    float s = 0.f;
    for (int i = 0; i < SEQ; ++i) s += attn_sh[i];
    fnorm_sh = (s > 0.f) ? 1.f / s : 1.f;
  }
  __syncthreads();
  float f = fnorm_sh;
  float a0 = 0, a1 = 0, a2 = 0, a3 = 0;
  const float4* ep = reinterpret_cast<const float4*>(enc + (size_t)b*SEQ*H2);
  for (int s = 0; s < SEQ; ++s) {
    float a = attn_sh[s];
    if (a != 0.f) {                       // block-uniform, almost always skipped
      a *= f;
      float4 v = ep[(size_t)s*(H2/4) + tid];
      a0 += a*v.x; a1 += a*v.y; a2 += a*v.z; a3 += a*v.w;
    }
  }
  float4 o = {a0, a1, a2, a3};
  reinterpret_cast<float4*>(wnew + (size_t)b*H2)[tid] = o;
}

// ---------------------------------------------------------------------------
extern "C" void kernel_launch(void* const* d_in, const int* in_sizes, int n_in,
                              void* d_out, int out_size, void* d_ws, size_t ws_size,
                              hipStream_t stream) {
  (void)in_sizes; (void)n_in; (void)out_size; (void)ws_size;
  const int*   input_idx  = (const int*)d_in[0];
  const float* encoded    = (const float*)d_in[1];
  const int*   enc_idx    = (const int*)d_in[2];
  const float* prev_state = (const float*)d_in[3];
  const float* weighted   = (const float*)d_in[4];
  const float* embed      = (const float*)d_in[6];
  const float* w_ih       = (const float*)d_in[7];
  const float* w_hh       = (const float*)d_in[8];
  const float* b_ih       = (const float*)d_in[9];
  const float* b_hh       = (const float*)d_in[10];
  const float* wo_w       = (const float*)d_in[11];
  const float* wo_b       = (const float*)d_in[12];
  const float* wc_w       = (const float*)d_in[13];
  const float* wc_b       = (const float*)d_in[14];

  float* out0      = (float*)d_out;                          // 64 x 50000
  float* out_state = out0 + (size_t)BATCH * VOCAB;           // 64 x 512
  float* out_wnew  = out_state + BATCH * HIDDEN;             // 64 x 1024

  // ws: [region0: gxp(8x64x1536) + ghp(4x64x1536) | aliased by Sg(64x50000)]
  //     [scc 64x200][pstats 64x16]
  float* ws    = (float*)d_ws;
  float* gxp   = ws;                                   // dead after gru_gates
  float* ghp   = ws + (size_t)8 * BATCH * G3;          // dead after gru_gates
  float* Sg    = ws;                                   // written after both die
  float* scc   = ws + (size_t)BATCH * VOCAB;           // 64x200
  float* pstats= scc + BATCH * SEQ;                    // 64x16

  gru_gemm<<<dim3(G3/64, 12), 256, 0, stream>>>(input_idx, embed, weighted, prev_state,
                                                w_ih, w_hh, gxp, ghp);
  gru_gates<<<(BATCH*HIDDEN)/256, 256, 0, stream>>>(gxp, ghp, b_ih, b_hh, prev_state, out_state);
  gemm_vocab<<<(VOCAB + 63)/64, 256, 0, stream>>>(out_state, wo_w, wo_b, Sg);
  stats_scc<<<BATCH * NPART, 256, 0, stream>>>(Sg, enc_idx, input_idx, encoded,
                                               wc_w, wc_b, out_state, scc, pstats);
  finalize_out<<<(BATCH*VOCAB/4)/256, 256, 0, stream>>>(Sg, pstats, out0);
  epilogue<<<BATCH, 256, 0, stream>>>(enc_idx, input_idx, scc, pstats, encoded, out0, out_wnew);
}